// Round 12
// baseline (334.288 us; speedup 1.0000x reference)
//
#include <hip/hip_runtime.h>

#define N_NODES 50000
#define C1 64    // in channels
#define C2 128   // hidden
#define C3 64    // latent / out
#define NBUCK 782                     // coarse buckets of 64 dst nodes
#define BCAP 8160                     // static slots per bucket (mean 2046, sigma 45 -> 134 sigma)
#define STILE 2048                    // edges per scatter block (8 per thread)

__device__ __forceinline__ float bf2f(unsigned short u) {
    union { unsigned int i; float f; } v; v.i = ((unsigned int)u) << 16; return v.f;
}
__device__ __forceinline__ unsigned short f2bf(float f) {
    union { float f; unsigned int i; } v; v.f = f;
    return (unsigned short)((v.i + 0x7FFFu + ((v.i >> 16) & 1u)) >> 16);
}
__device__ __forceinline__ float hi2f(unsigned int p) {
    union { unsigned int i; float f; } v; v.i = p & 0xFFFF0000u; return v.f;
}

// ---------------- zero cursors + stats, cast x -> bf16 ----------------
__global__ void k_zero_cast(const float* __restrict__ x, unsigned short* __restrict__ xh,
                            int* __restrict__ bcursor, float* __restrict__ stats) {
    int i = blockIdx.x * blockDim.x + threadIdx.x;
    if (i < NBUCK * 16) bcursor[i] = 0;
    if (i < 512) stats[i] = 0.0f;
    if (i < N_NODES * C1 / 4) {
        float4 v = ((const float4*)x)[i];
        ushort4 o;
        o.x = f2bf(v.x); o.y = f2bf(v.y); o.z = f2bf(v.z); o.w = f2bf(v.w);
        ((ushort4*)xh)[i] = o;
    }
}

// ---------------- coarse scatter: per-wave sub-histograms, static bucket segments ----------------
__global__ __launch_bounds__(256) void k_scatterc(const int* __restrict__ src,
                                                  const int* __restrict__ dst, int E,
                                                  int* __restrict__ bcursor,
                                                  int* __restrict__ pairs) {
    __shared__ int lh[4][NBUCK];  // per-wave histograms -> per-wave exclusive prefixes
    __shared__ int gbase[NBUCK];  // per-block reserved run base
    int tid = threadIdx.x, wid = tid >> 6;
    int base = blockIdx.x * STILE;
    for (int i = tid; i < NBUCK; i += 256) {
        lh[0][i] = 0; lh[1][i] = 0; lh[2][i] = 0; lh[3][i] = 0;
    }
    __syncthreads();
    int sv[8], dv[8], rk[8];
#pragma unroll
    for (int k = 0; k < 8; ++k) {
        int e = base + k * 256 + tid;
        sv[k] = -1;
        if (e < E) {
            sv[k] = src[e];
            dv[k] = dst[e];
            rk[k] = atomicAdd(&lh[wid][dv[k] >> 6], 1);
        }
    }
    __syncthreads();
    for (int i = tid; i < NBUCK; i += 256) {
        int c0 = lh[0][i], c1 = lh[1][i], c2 = lh[2][i], c3 = lh[3][i];
        int tot = c0 + c1 + c2 + c3;
        gbase[i] = tot ? atomicAdd(&bcursor[i * 16], tot) : 0;
        lh[0][i] = 0; lh[1][i] = c0; lh[2][i] = c0 + c1; lh[3][i] = c0 + c1 + c2;
    }
    __syncthreads();
#pragma unroll
    for (int k = 0; k < 8; ++k) {
        if (sv[k] >= 0) {
            int b = dv[k] >> 6;
            pairs[b * BCAP + gbase[b] + lh[wid][b] + rk[k]] = (sv[k] << 6) | (dv[k] & 63);
        }
    }
}

// ---------------- scan 782 bucket counts -> compact bases ----------------
__global__ __launch_bounds__(1024) void k_scanb(const int* __restrict__ bcursor,
                                                int* __restrict__ cbase) {
    __shared__ int sums[1024];
    int t = threadIdx.x;
    int v = (t < NBUCK) ? bcursor[t * 16] : 0;
    sums[t] = v;
    __syncthreads();
    for (int off = 1; off < 1024; off <<= 1) {
        int u = (t >= off) ? sums[t - off] : 0;
        __syncthreads();
        sums[t] += u;
        __syncthreads();
    }
    if (t < NBUCK) cbase[t] = sums[t] - v;
}

// ---------------- refine: static bucket -> COMPACT node-major csr; rowstart + dinv ----------------
__global__ __launch_bounds__(256) void k_refine(const int* __restrict__ bcursor,
                                                const int* __restrict__ cbase,
                                                int* __restrict__ rowstart,
                                                float* __restrict__ dinv,
                                                const int* __restrict__ pairs,
                                                int* __restrict__ csr) {
    __shared__ int stage[BCAP];   // ~32 KB
    __shared__ int lcnt[64];
    __shared__ int lcur[64];
    int b = blockIdx.x;
    int tid = threadIdx.x;
    int n = bcursor[b * 16];
    int e0s = b * BCAP;   // static read base
    int c0 = cbase[b];    // compact write base
    if (tid < 64) lcnt[tid] = 0;
    __syncthreads();
    for (int j = tid; j < n; j += 256) {
        int pk = pairs[e0s + j];
        stage[j] = pk;
        atomicAdd(&lcnt[pk & 63], 1);
    }
    __syncthreads();
    if (tid < 64) {   // wave 0: shfl-scan the 64 local degrees
        int dg = lcnt[tid];
        int pfx = dg;
#pragma unroll
        for (int off = 1; off < 64; off <<= 1) {
            int v = __shfl_up(pfx, off);
            if (tid >= off) pfx += v;
        }
        int st = c0 + (pfx - dg);   // exclusive, compact space
        int nd = b * 64 + tid;
        rowstart[nd] = st;          // padding slots get valid boundaries too
        dinv[nd] = rsqrtf(1.0f + (float)dg);
        lcur[tid] = st;
    }
    __syncthreads();
    for (int j = tid; j < n; j += 256) {
        int pk = stage[j];
        int pos = atomicAdd(&lcur[pk & 63], 1);
        csr[pos] = pk >> 6;   // compact, node-major
    }
}

// ---------------- pack per-edge word: bf16(dinv[src])<<16 | src (compact space) ----------------
__global__ void k_pack(const int* __restrict__ csr, const float* __restrict__ dinv,
                       unsigned int* __restrict__ wsrc, int E) {
    int j = blockIdx.x * blockDim.x + threadIdx.x;
    if (j < E) {
        int s = csr[j];
        wsrc[j] = ((unsigned int)f2bf(dinv[s]) << 16) | (unsigned int)s;
    }
}

// ---------------- pull x: LDS-staged broadcast, 8-deep gather pipeline ----------------
__global__ __launch_bounds__(256) void k_pullx(const int* __restrict__ rowstart,
                                               const unsigned int* __restrict__ wsrc,
                                               const float* __restrict__ x,
                                               const unsigned short* __restrict__ xh,
                                               const float* __restrict__ dinv,
                                               float* __restrict__ aggx) {
    __shared__ unsigned int sp[4][64];
    int wid = threadIdx.x >> 6, lane = threadIdx.x & 63;
    int node = blockIdx.x * 4 + wid;
    if (node >= N_NODES) return;
    int start = rowstart[node], end = rowstart[node + 1];
    float dd = dinv[node];
    float a0 = 0.0f, a1 = 0.0f, a2 = 0.0f, a3 = 0.0f;
    for (int j0 = start; j0 < end; j0 += 64) {
        int n = end - j0; if (n > 64) n = 64;
        if (lane < n) sp[wid][lane] = wsrc[j0 + lane];
        int k = 0;
        for (; k + 7 < n; k += 8) {
            unsigned int p0 = sp[wid][k],     p1 = sp[wid][k + 1];
            unsigned int p2 = sp[wid][k + 2], p3 = sp[wid][k + 3];
            unsigned int p4 = sp[wid][k + 4], p5 = sp[wid][k + 5];
            unsigned int p6 = sp[wid][k + 6], p7 = sp[wid][k + 7];
            float v0 = bf2f(xh[(p0 & 0xFFFFu) * C1 + lane]);
            float v1 = bf2f(xh[(p1 & 0xFFFFu) * C1 + lane]);
            float v2 = bf2f(xh[(p2 & 0xFFFFu) * C1 + lane]);
            float v3 = bf2f(xh[(p3 & 0xFFFFu) * C1 + lane]);
            float v4 = bf2f(xh[(p4 & 0xFFFFu) * C1 + lane]);
            float v5 = bf2f(xh[(p5 & 0xFFFFu) * C1 + lane]);
            float v6 = bf2f(xh[(p6 & 0xFFFFu) * C1 + lane]);
            float v7 = bf2f(xh[(p7 & 0xFFFFu) * C1 + lane]);
            a0 = fmaf(v0, hi2f(p0), a0); a1 = fmaf(v1, hi2f(p1), a1);
            a2 = fmaf(v2, hi2f(p2), a2); a3 = fmaf(v3, hi2f(p3), a3);
            a0 = fmaf(v4, hi2f(p4), a0); a1 = fmaf(v5, hi2f(p5), a1);
            a2 = fmaf(v6, hi2f(p6), a2); a3 = fmaf(v7, hi2f(p7), a3);
        }
        for (; k < n; ++k) {
            unsigned int p = sp[wid][k];
            a0 = fmaf(bf2f(xh[(p & 0xFFFFu) * C1 + lane]), hi2f(p), a0);
        }
    }
    float eacc = (a0 + a1) + (a2 + a3);
    aggx[node * C1 + lane] = fmaf(x[node * C1 + lane], dd * dd, dd * eacc);
}

// ---------------- GEMM1: agg1 = aggx @ W1 + b1 ----------------
__global__ __launch_bounds__(256) void k_gemm1b(const float* __restrict__ aggx,
                                                const float* __restrict__ W1,
                                                const float* __restrict__ b1,
                                                float* __restrict__ agg1) {
    __shared__ float Ws[C1 * C2];   // 32 KB
    __shared__ float Xs[32 * C1];   //  8 KB
    int tid = threadIdx.x;
    int r0 = blockIdx.x * 32;
    for (int i = tid; i < C1 * C2; i += 256) Ws[i] = W1[i];
    for (int i = tid; i < 32 * C1; i += 256) {
        int row = r0 + (i >> 6);
        Xs[i] = (row < N_NODES) ? aggx[row * C1 + (i & 63)] : 0.0f;
    }
    __syncthreads();
    int c = tid & 127;
    int rg = tid >> 7;
    float bv = b1[c];
    float acc[16];
#pragma unroll
    for (int r = 0; r < 16; ++r) acc[r] = 0.0f;
    for (int k = 0; k < C1; ++k) {
        float w = Ws[k * C2 + c];
#pragma unroll
        for (int r = 0; r < 16; ++r)
            acc[r] = fmaf(Xs[(rg * 16 + r) * C1 + k], w, acc[r]);
    }
#pragma unroll
    for (int r = 0; r < 16; ++r) {
        int row = r0 + rg * 16 + r;
        if (row < N_NODES) agg1[row * C2 + c] = acc[r] + bv;
    }
}

// ---------------- BN stats ----------------
__global__ __launch_bounds__(256) void k_stats(const float* __restrict__ agg1,
                                               float* __restrict__ stats) {
    __shared__ float ls[256], lq[256];
    int tid = threadIdx.x;
    int c = tid & 127, half = tid >> 7;
    float s = 0.0f, q = 0.0f;
    for (int row = blockIdx.x * 2 + half; row < N_NODES; row += gridDim.x * 2) {
        float v = agg1[row * C2 + c];
        s += v; q += v * v;
    }
    ls[tid] = s; lq[tid] = q;
    __syncthreads();
    if (tid < 128) {
        s = ls[tid] + ls[tid + 128];
        q = lq[tid] + lq[tid + 128];
        unsafeAtomicAdd(&stats[c], s);
        unsafeAtomicAdd(&stats[128 + c], q);
    }
}

__global__ void k_bnparam(const float* __restrict__ gamma, const float* __restrict__ beta,
                          float* __restrict__ stats) {
    int c = threadIdx.x;
    if (c < 128) {
        const float invN = 1.0f / (float)N_NODES;
        float mean = stats[c] * invN;
        float var = stats[128 + c] * invN - mean * mean;
        float sc = gamma[c] * rsqrtf(var + 1e-5f);
        stats[256 + c] = sc;
        stats[384 + c] = beta[c] - mean * sc;
    }
}

// ---------------- GEMM2: h2 = relu(bn(agg1)) @ W2, bf16 output ----------------
__global__ __launch_bounds__(256) void k_gemm2(const float* __restrict__ agg1,
                                               const float* __restrict__ W2,
                                               const float* __restrict__ stats,
                                               unsigned short* __restrict__ h2h) {
    __shared__ float Ws[C2 * C3];   // 32 KB
    __shared__ float As[32 * C2];   // 16 KB
    int tid = threadIdx.x;
    int r0 = blockIdx.x * 32;
    for (int i = tid; i < C2 * C3; i += 256) Ws[i] = W2[i];
    for (int i = tid; i < 32 * C2; i += 256) {
        int row = r0 + (i >> 7);
        int cc = i & 127;
        float v = 0.0f;
        if (row < N_NODES)
            v = fmaxf(fmaf(agg1[row * C2 + cc], stats[256 + cc], stats[384 + cc]), 0.0f);
        As[i] = v;
    }
    __syncthreads();
    int c = tid & 63;
    int rg = tid >> 6;
    float acc[8];
#pragma unroll
    for (int r = 0; r < 8; ++r) acc[r] = 0.0f;
    for (int k = 0; k < C2; ++k) {
        float w = Ws[k * C3 + c];
#pragma unroll
        for (int r = 0; r < 8; ++r)
            acc[r] = fmaf(As[(rg * 8 + r) * C2 + k], w, acc[r]);
    }
#pragma unroll
    for (int r = 0; r < 8; ++r) {
        int row = r0 + rg * 8 + r;
        if (row < N_NODES) h2h[row * C3 + c] = f2bf(acc[r]);
    }
}

// ---------------- pull layer 2: LDS-staged broadcast, 8-deep ----------------
__global__ __launch_bounds__(256) void k_pull2(const int* __restrict__ rowstart,
                                               const unsigned int* __restrict__ wsrc,
                                               const unsigned short* __restrict__ h2h,
                                               const float* __restrict__ dinv,
                                               const float* __restrict__ b2,
                                               float* __restrict__ out) {
    __shared__ unsigned int sp[4][64];
    int wid = threadIdx.x >> 6, lane = threadIdx.x & 63;
    int node = blockIdx.x * 4 + wid;
    if (node >= N_NODES) return;
    int start = rowstart[node], end = rowstart[node + 1];
    float dd = dinv[node];
    float a0 = 0.0f, a1 = 0.0f, a2 = 0.0f, a3 = 0.0f;
    for (int j0 = start; j0 < end; j0 += 64) {
        int n = end - j0; if (n > 64) n = 64;
        if (lane < n) sp[wid][lane] = wsrc[j0 + lane];
        int k = 0;
        for (; k + 7 < n; k += 8) {
            unsigned int p0 = sp[wid][k],     p1 = sp[wid][k + 1];
            unsigned int p2 = sp[wid][k + 2], p3 = sp[wid][k + 3];
            unsigned int p4 = sp[wid][k + 4], p5 = sp[wid][k + 5];
            unsigned int p6 = sp[wid][k + 6], p7 = sp[wid][k + 7];
            float v0 = bf2f(h2h[(p0 & 0xFFFFu) * C3 + lane]);
            float v1 = bf2f(h2h[(p1 & 0xFFFFu) * C3 + lane]);
            float v2 = bf2f(h2h[(p2 & 0xFFFFu) * C3 + lane]);
            float v3 = bf2f(h2h[(p3 & 0xFFFFu) * C3 + lane]);
            float v4 = bf2f(h2h[(p4 & 0xFFFFu) * C3 + lane]);
            float v5 = bf2f(h2h[(p5 & 0xFFFFu) * C3 + lane]);
            float v6 = bf2f(h2h[(p6 & 0xFFFFu) * C3 + lane]);
            float v7 = bf2f(h2h[(p7 & 0xFFFFu) * C3 + lane]);
            a0 = fmaf(v0, hi2f(p0), a0); a1 = fmaf(v1, hi2f(p1), a1);
            a2 = fmaf(v2, hi2f(p2), a2); a3 = fmaf(v3, hi2f(p3), a3);
            a0 = fmaf(v4, hi2f(p4), a0); a1 = fmaf(v5, hi2f(p5), a1);
            a2 = fmaf(v6, hi2f(p6), a2); a3 = fmaf(v7, hi2f(p7), a3);
        }
        for (; k < n; ++k) {
            unsigned int p = sp[wid][k];
            a0 = fmaf(bf2f(h2h[(p & 0xFFFFu) * C3 + lane]), hi2f(p), a0);
        }
    }
    float eacc = (a0 + a1) + (a2 + a3);
    float self = bf2f(h2h[node * C3 + lane]);
    out[node * C3 + lane] = b2[lane] + fmaf(self, dd * dd, dd * eacc);
}

extern "C" void kernel_launch(void* const* d_in, const int* in_sizes, int n_in,
                              void* d_out, int out_size, void* d_ws, size_t ws_size,
                              hipStream_t stream) {
    const float* x     = (const float*)d_in[0];
    const int*   ei    = (const int*)d_in[1];
    const float* W1    = (const float*)d_in[2];
    const float* b1    = (const float*)d_in[3];
    const float* gamma = (const float*)d_in[4];
    const float* beta  = (const float*)d_in[5];
    const float* W2    = (const float*)d_in[6];
    const float* b2    = (const float*)d_in[7];
    float* out = (float*)d_out;

    int E = in_sizes[1] / 2;
    const int* src = ei;
    const int* dst = ei + E;

    // workspace layout (bytes), total ~58.1MB (overlaps noted):
    //   0         dinv      [50176 f]    200704
    //   200704    stats     [512 f]      2048
    //   202752    bcursor   [782*16 i]   50176 (1 cursor / 64B line, zero-init)
    //   252928    cbase     [1024 i]     4096
    //   257024    rowstart  [50176 i]    200704
    //   457728    wsrc      [1.6M u]     6400000
    //   6857728   xh (bf16) [50000*64]   6400000
    //   13257728  aggx      [50000*64]   12800000  (csr_compact = first 6.4MB; dead before pullx writes)
    //   26057728  agg1      [50000*128]  25600000  (pairs_static 782*8160*4=25524480 overlays; dead before gemm1b)
    //   51657728  h2h (bf16)[50000*64]   6400000   -> end 58057728
    char* ws = (char*)d_ws;
    float*          dinv     = (float*)ws;
    float*          stats    = (float*)(ws + 200704);
    int*            bcursor  = (int*)(ws + 202752);
    int*            cbase    = (int*)(ws + 252928);
    int*            rowstart = (int*)(ws + 257024);
    unsigned int*   wsrc     = (unsigned int*)(ws + 457728);
    unsigned short* xh       = (unsigned short*)(ws + 6857728);
    float*          aggx     = (float*)(ws + 13257728);
    int*            csr      = (int*)(ws + 13257728);     // overlays aggx (dead before pullx)
    float*          agg1     = (float*)(ws + 26057728);
    int*            pairs    = (int*)(ws + 26057728);     // overlays agg1 (dead before gemm1b)
    unsigned short* h2h      = (unsigned short*)(ws + 51657728);

    const int nblk_cast  = (N_NODES * C1 / 4 + 255) / 256;   // 3125
    const int nblk_rows  = (N_NODES + 31) / 32;
    const int nblk_scat  = (E + STILE - 1) / STILE;          // 782
    const int nblk_edge  = (E + 255) / 256;
    const int nblk_pull  = (N_NODES + 3) / 4;

    k_zero_cast<<<nblk_cast, 256, 0, stream>>>(x, xh, bcursor, stats);
    k_scatterc<<<nblk_scat, 256, 0, stream>>>(src, dst, E, bcursor, pairs);
    k_scanb<<<1, 1024, 0, stream>>>(bcursor, cbase);
    k_refine<<<NBUCK, 256, 0, stream>>>(bcursor, cbase, rowstart, dinv, pairs, csr);
    k_pack<<<nblk_edge, 256, 0, stream>>>(csr, dinv, wsrc, E);

    k_pullx<<<nblk_pull, 256, 0, stream>>>(rowstart, wsrc, x, xh, dinv, aggx);
    k_gemm1b<<<nblk_rows, 256, 0, stream>>>(aggx, W1, b1, agg1);

    k_stats<<<256, 256, 0, stream>>>(agg1, stats);
    k_bnparam<<<1, 128, 0, stream>>>(gamma, beta, stats);

    k_gemm2<<<nblk_rows, 256, 0, stream>>>(agg1, W2, stats, h2h);
    k_pull2<<<nblk_pull, 256, 0, stream>>>(rowstart, wsrc, h2h, dinv, b2, out);
}

// Round 13
// 302.880 us; speedup vs baseline: 1.1037x; 1.1037x over previous
//
#include <hip/hip_runtime.h>

#define N_NODES 50000
#define C1 64    // in channels
#define C2 128   // hidden
#define C3 64    // latent / out
#define NBUCK 196                     // coarse buckets of 256 dst nodes
#define BCAP 10240                    // static slots per bucket (mean 8163, sigma 90 -> 23 sigma)
#define STILE 4096                    // edges per scatter block (16 per thread)

__device__ __forceinline__ float bf2f(unsigned short u) {
    union { unsigned int i; float f; } v; v.i = ((unsigned int)u) << 16; return v.f;
}
__device__ __forceinline__ unsigned short f2bf(float f) {
    union { float f; unsigned int i; } v; v.f = f;
    return (unsigned short)((v.i + 0x7FFFu + ((v.i >> 16) & 1u)) >> 16);
}
__device__ __forceinline__ float hi2f(unsigned int p) {
    union { unsigned int i; float f; } v; v.i = p & 0xFFFF0000u; return v.f;
}

// ---------------- zero cursors + stats, cast x -> bf16 ----------------
__global__ void k_zero_cast(const float* __restrict__ x, unsigned short* __restrict__ xh,
                            int* __restrict__ bcursor, float* __restrict__ stats) {
    int i = blockIdx.x * blockDim.x + threadIdx.x;
    if (i < NBUCK * 16) bcursor[i] = 0;
    if (i < 512) stats[i] = 0.0f;
    if (i < N_NODES * C1 / 4) {
        float4 v = ((const float4*)x)[i];
        ushort4 o;
        o.x = f2bf(v.x); o.y = f2bf(v.y); o.z = f2bf(v.z); o.w = f2bf(v.w);
        ((ushort4*)xh)[i] = o;
    }
}

// ---------------- coarse scatter: 196 big buckets, per-wave histograms ----------------
__global__ __launch_bounds__(256) void k_scatterc(const int* __restrict__ src,
                                                  const int* __restrict__ dst, int E,
                                                  int* __restrict__ bcursor,
                                                  int* __restrict__ pairs) {
    __shared__ int lh[4][NBUCK];  // per-wave histograms -> per-wave exclusive prefixes
    __shared__ int gbase[NBUCK];  // per-block reserved run base
    int tid = threadIdx.x, wid = tid >> 6;
    int base = blockIdx.x * STILE;
    for (int i = tid; i < NBUCK; i += 256) {
        lh[0][i] = 0; lh[1][i] = 0; lh[2][i] = 0; lh[3][i] = 0;
    }
    __syncthreads();
    int sv[16], dv[16], rk[16];
#pragma unroll
    for (int k = 0; k < 16; ++k) {
        int e = base + k * 256 + tid;
        sv[k] = -1;
        if (e < E) {
            sv[k] = src[e];
            dv[k] = dst[e];
            rk[k] = atomicAdd(&lh[wid][dv[k] >> 8], 1);
        }
    }
    __syncthreads();
    for (int i = tid; i < NBUCK; i += 256) {
        int c0 = lh[0][i], c1 = lh[1][i], c2 = lh[2][i], c3 = lh[3][i];
        int tot = c0 + c1 + c2 + c3;
        gbase[i] = tot ? atomicAdd(&bcursor[i * 16], tot) : 0;
        lh[0][i] = 0; lh[1][i] = c0; lh[2][i] = c0 + c1; lh[3][i] = c0 + c1 + c2;
    }
    __syncthreads();
#pragma unroll
    for (int k = 0; k < 16; ++k) {
        if (sv[k] >= 0) {
            int b = dv[k] >> 8;
            pairs[b * BCAP + gbase[b] + lh[wid][b] + rk[k]] = (sv[k] << 8) | (dv[k] & 255);
        }
    }
}

// ---------------- scan 196 bucket counts -> compact bases ----------------
__global__ __launch_bounds__(256) void k_scanb(const int* __restrict__ bcursor,
                                               int* __restrict__ cbase) {
    __shared__ int sums[256];
    int t = threadIdx.x;
    int v = (t < NBUCK) ? bcursor[t * 16] : 0;
    sums[t] = v;
    __syncthreads();
    for (int off = 1; off < 256; off <<= 1) {
        int u = (t >= off) ? sums[t - off] : 0;
        __syncthreads();
        sums[t] += u;
        __syncthreads();
    }
    if (t < NBUCK) cbase[t] = sums[t] - v;
}

// ---------------- refine: 256-node buckets, two-pass, compact node-major csr ----------------
__global__ __launch_bounds__(256) void k_refine(const int* __restrict__ bcursor,
                                                const int* __restrict__ cbase,
                                                int* __restrict__ rowstart,
                                                float* __restrict__ dinv,
                                                const int* __restrict__ pairs,
                                                int* __restrict__ csr) {
    __shared__ int lcnt[256];
    __shared__ int lcur[256];
    __shared__ int wtot[4];
    int b = blockIdx.x;
    int tid = threadIdx.x, wid = tid >> 6, lane = tid & 63;
    int n = bcursor[b * 16];
    int e0s = b * BCAP;   // static read base
    int c0 = cbase[b];    // compact write base
    lcnt[tid] = 0;
    __syncthreads();
    // pass 1: count local degrees
    for (int j = tid; j < n; j += 256) {
        int pk = pairs[e0s + j];
        atomicAdd(&lcnt[pk & 255], 1);
    }
    __syncthreads();
    // scan 256 degrees: wave-scan + cross-wave combine
    int dg = lcnt[tid];
    int pfx = dg;
#pragma unroll
    for (int off = 1; off < 64; off <<= 1) {
        int v = __shfl_up(pfx, off);
        if (lane >= off) pfx += v;
    }
    if (lane == 63) wtot[wid] = pfx;
    __syncthreads();
    int wbase = 0;
    for (int w = 0; w < 4; ++w) if (w < wid) wbase += wtot[w];
    int st = c0 + wbase + (pfx - dg);   // exclusive, compact space
    int nd = b * 256 + tid;             // nd <= 50175 < 50176, write unguarded
    rowstart[nd] = st;
    dinv[nd] = rsqrtf(1.0f + (float)dg);
    lcur[tid] = st;
    __syncthreads();
    // pass 2: scatter to node-major compact csr
    for (int j = tid; j < n; j += 256) {
        int pk = pairs[e0s + j];
        int pos = atomicAdd(&lcur[pk & 255], 1);
        csr[pos] = pk >> 8;
    }
}

// ---------------- pack per-edge word: bf16(dinv[src])<<16 | src (compact space) ----------------
__global__ void k_pack(const int* __restrict__ csr, const float* __restrict__ dinv,
                       unsigned int* __restrict__ wsrc, int E) {
    int j = blockIdx.x * blockDim.x + threadIdx.x;
    if (j < E) {
        int s = csr[j];
        wsrc[j] = ((unsigned int)f2bf(dinv[s]) << 16) | (unsigned int)s;
    }
}

// ---------------- pull x: LDS-staged broadcast, 8-deep gather pipeline ----------------
__global__ __launch_bounds__(256) void k_pullx(const int* __restrict__ rowstart,
                                               const unsigned int* __restrict__ wsrc,
                                               const float* __restrict__ x,
                                               const unsigned short* __restrict__ xh,
                                               const float* __restrict__ dinv,
                                               float* __restrict__ aggx) {
    __shared__ unsigned int sp[4][64];
    int wid = threadIdx.x >> 6, lane = threadIdx.x & 63;
    int node = blockIdx.x * 4 + wid;
    if (node >= N_NODES) return;
    int start = rowstart[node], end = rowstart[node + 1];
    float dd = dinv[node];
    float a0 = 0.0f, a1 = 0.0f, a2 = 0.0f, a3 = 0.0f;
    for (int j0 = start; j0 < end; j0 += 64) {
        int n = end - j0; if (n > 64) n = 64;
        if (lane < n) sp[wid][lane] = wsrc[j0 + lane];
        int k = 0;
        for (; k + 7 < n; k += 8) {
            unsigned int p0 = sp[wid][k],     p1 = sp[wid][k + 1];
            unsigned int p2 = sp[wid][k + 2], p3 = sp[wid][k + 3];
            unsigned int p4 = sp[wid][k + 4], p5 = sp[wid][k + 5];
            unsigned int p6 = sp[wid][k + 6], p7 = sp[wid][k + 7];
            float v0 = bf2f(xh[(p0 & 0xFFFFu) * C1 + lane]);
            float v1 = bf2f(xh[(p1 & 0xFFFFu) * C1 + lane]);
            float v2 = bf2f(xh[(p2 & 0xFFFFu) * C1 + lane]);
            float v3 = bf2f(xh[(p3 & 0xFFFFu) * C1 + lane]);
            float v4 = bf2f(xh[(p4 & 0xFFFFu) * C1 + lane]);
            float v5 = bf2f(xh[(p5 & 0xFFFFu) * C1 + lane]);
            float v6 = bf2f(xh[(p6 & 0xFFFFu) * C1 + lane]);
            float v7 = bf2f(xh[(p7 & 0xFFFFu) * C1 + lane]);
            a0 = fmaf(v0, hi2f(p0), a0); a1 = fmaf(v1, hi2f(p1), a1);
            a2 = fmaf(v2, hi2f(p2), a2); a3 = fmaf(v3, hi2f(p3), a3);
            a0 = fmaf(v4, hi2f(p4), a0); a1 = fmaf(v5, hi2f(p5), a1);
            a2 = fmaf(v6, hi2f(p6), a2); a3 = fmaf(v7, hi2f(p7), a3);
        }
        for (; k < n; ++k) {
            unsigned int p = sp[wid][k];
            a0 = fmaf(bf2f(xh[(p & 0xFFFFu) * C1 + lane]), hi2f(p), a0);
        }
    }
    float eacc = (a0 + a1) + (a2 + a3);
    aggx[node * C1 + lane] = fmaf(x[node * C1 + lane], dd * dd, dd * eacc);
}

// ---------------- GEMM1: agg1 = aggx @ W1 + b1 ----------------
__global__ __launch_bounds__(256) void k_gemm1b(const float* __restrict__ aggx,
                                                const float* __restrict__ W1,
                                                const float* __restrict__ b1,
                                                float* __restrict__ agg1) {
    __shared__ float Ws[C1 * C2];   // 32 KB
    __shared__ float Xs[32 * C1];   //  8 KB
    int tid = threadIdx.x;
    int r0 = blockIdx.x * 32;
    for (int i = tid; i < C1 * C2; i += 256) Ws[i] = W1[i];
    for (int i = tid; i < 32 * C1; i += 256) {
        int row = r0 + (i >> 6);
        Xs[i] = (row < N_NODES) ? aggx[row * C1 + (i & 63)] : 0.0f;
    }
    __syncthreads();
    int c = tid & 127;
    int rg = tid >> 7;
    float bv = b1[c];
    float acc[16];
#pragma unroll
    for (int r = 0; r < 16; ++r) acc[r] = 0.0f;
    for (int k = 0; k < C1; ++k) {
        float w = Ws[k * C2 + c];
#pragma unroll
        for (int r = 0; r < 16; ++r)
            acc[r] = fmaf(Xs[(rg * 16 + r) * C1 + k], w, acc[r]);
    }
#pragma unroll
    for (int r = 0; r < 16; ++r) {
        int row = r0 + rg * 16 + r;
        if (row < N_NODES) agg1[row * C2 + c] = acc[r] + bv;
    }
}

// ---------------- BN stats ----------------
__global__ __launch_bounds__(256) void k_stats(const float* __restrict__ agg1,
                                               float* __restrict__ stats) {
    __shared__ float ls[256], lq[256];
    int tid = threadIdx.x;
    int c = tid & 127, half = tid >> 7;
    float s = 0.0f, q = 0.0f;
    for (int row = blockIdx.x * 2 + half; row < N_NODES; row += gridDim.x * 2) {
        float v = agg1[row * C2 + c];
        s += v; q += v * v;
    }
    ls[tid] = s; lq[tid] = q;
    __syncthreads();
    if (tid < 128) {
        s = ls[tid] + ls[tid + 128];
        q = lq[tid] + lq[tid + 128];
        unsafeAtomicAdd(&stats[c], s);
        unsafeAtomicAdd(&stats[128 + c], q);
    }
}

__global__ void k_bnparam(const float* __restrict__ gamma, const float* __restrict__ beta,
                          float* __restrict__ stats) {
    int c = threadIdx.x;
    if (c < 128) {
        const float invN = 1.0f / (float)N_NODES;
        float mean = stats[c] * invN;
        float var = stats[128 + c] * invN - mean * mean;
        float sc = gamma[c] * rsqrtf(var + 1e-5f);
        stats[256 + c] = sc;
        stats[384 + c] = beta[c] - mean * sc;
    }
}

// ---------------- GEMM2: h2 = relu(bn(agg1)) @ W2, bf16 output ----------------
__global__ __launch_bounds__(256) void k_gemm2(const float* __restrict__ agg1,
                                               const float* __restrict__ W2,
                                               const float* __restrict__ stats,
                                               unsigned short* __restrict__ h2h) {
    __shared__ float Ws[C2 * C3];   // 32 KB
    __shared__ float As[32 * C2];   // 16 KB
    int tid = threadIdx.x;
    int r0 = blockIdx.x * 32;
    for (int i = tid; i < C2 * C3; i += 256) Ws[i] = W2[i];
    for (int i = tid; i < 32 * C2; i += 256) {
        int row = r0 + (i >> 7);
        int cc = i & 127;
        float v = 0.0f;
        if (row < N_NODES)
            v = fmaxf(fmaf(agg1[row * C2 + cc], stats[256 + cc], stats[384 + cc]), 0.0f);
        As[i] = v;
    }
    __syncthreads();
    int c = tid & 63;
    int rg = tid >> 6;
    float acc[8];
#pragma unroll
    for (int r = 0; r < 8; ++r) acc[r] = 0.0f;
    for (int k = 0; k < C2; ++k) {
        float w = Ws[k * C3 + c];
#pragma unroll
        for (int r = 0; r < 8; ++r)
            acc[r] = fmaf(As[(rg * 8 + r) * C2 + k], w, acc[r]);
    }
#pragma unroll
    for (int r = 0; r < 8; ++r) {
        int row = r0 + rg * 8 + r;
        if (row < N_NODES) h2h[row * C3 + c] = f2bf(acc[r]);
    }
}

// ---------------- pull layer 2: LDS-staged broadcast, 8-deep ----------------
__global__ __launch_bounds__(256) void k_pull2(const int* __restrict__ rowstart,
                                               const unsigned int* __restrict__ wsrc,
                                               const unsigned short* __restrict__ h2h,
                                               const float* __restrict__ dinv,
                                               const float* __restrict__ b2,
                                               float* __restrict__ out) {
    __shared__ unsigned int sp[4][64];
    int wid = threadIdx.x >> 6, lane = threadIdx.x & 63;
    int node = blockIdx.x * 4 + wid;
    if (node >= N_NODES) return;
    int start = rowstart[node], end = rowstart[node + 1];
    float dd = dinv[node];
    float a0 = 0.0f, a1 = 0.0f, a2 = 0.0f, a3 = 0.0f;
    for (int j0 = start; j0 < end; j0 += 64) {
        int n = end - j0; if (n > 64) n = 64;
        if (lane < n) sp[wid][lane] = wsrc[j0 + lane];
        int k = 0;
        for (; k + 7 < n; k += 8) {
            unsigned int p0 = sp[wid][k],     p1 = sp[wid][k + 1];
            unsigned int p2 = sp[wid][k + 2], p3 = sp[wid][k + 3];
            unsigned int p4 = sp[wid][k + 4], p5 = sp[wid][k + 5];
            unsigned int p6 = sp[wid][k + 6], p7 = sp[wid][k + 7];
            float v0 = bf2f(h2h[(p0 & 0xFFFFu) * C3 + lane]);
            float v1 = bf2f(h2h[(p1 & 0xFFFFu) * C3 + lane]);
            float v2 = bf2f(h2h[(p2 & 0xFFFFu) * C3 + lane]);
            float v3 = bf2f(h2h[(p3 & 0xFFFFu) * C3 + lane]);
            float v4 = bf2f(h2h[(p4 & 0xFFFFu) * C3 + lane]);
            float v5 = bf2f(h2h[(p5 & 0xFFFFu) * C3 + lane]);
            float v6 = bf2f(h2h[(p6 & 0xFFFFu) * C3 + lane]);
            float v7 = bf2f(h2h[(p7 & 0xFFFFu) * C3 + lane]);
            a0 = fmaf(v0, hi2f(p0), a0); a1 = fmaf(v1, hi2f(p1), a1);
            a2 = fmaf(v2, hi2f(p2), a2); a3 = fmaf(v3, hi2f(p3), a3);
            a0 = fmaf(v4, hi2f(p4), a0); a1 = fmaf(v5, hi2f(p5), a1);
            a2 = fmaf(v6, hi2f(p6), a2); a3 = fmaf(v7, hi2f(p7), a3);
        }
        for (; k < n; ++k) {
            unsigned int p = sp[wid][k];
            a0 = fmaf(bf2f(h2h[(p & 0xFFFFu) * C3 + lane]), hi2f(p), a0);
        }
    }
    float eacc = (a0 + a1) + (a2 + a3);
    float self = bf2f(h2h[node * C3 + lane]);
    out[node * C3 + lane] = b2[lane] + fmaf(self, dd * dd, dd * eacc);
}

extern "C" void kernel_launch(void* const* d_in, const int* in_sizes, int n_in,
                              void* d_out, int out_size, void* d_ws, size_t ws_size,
                              hipStream_t stream) {
    const float* x     = (const float*)d_in[0];
    const int*   ei    = (const int*)d_in[1];
    const float* W1    = (const float*)d_in[2];
    const float* b1    = (const float*)d_in[3];
    const float* gamma = (const float*)d_in[4];
    const float* beta  = (const float*)d_in[5];
    const float* W2    = (const float*)d_in[6];
    const float* b2    = (const float*)d_in[7];
    float* out = (float*)d_out;

    int E = in_sizes[1] / 2;
    const int* src = ei;
    const int* dst = ei + E;

    // workspace layout (bytes), total ~58.0MB (overlaps noted):
    //   0         dinv      [50176 f]    200704
    //   200704    stats     [512 f]      2048
    //   202752    bcursor   [196*16 i]   12544 (1 cursor / 64B line, zero-init)
    //   215296    cbase     [1024 i]     4096
    //   219392    rowstart  [50176 i]    200704
    //   420096    wsrc      [1.6M u]     6400000
    //   6820096   xh (bf16) [50000*64]   6400000
    //   13220096  aggx      [50000*64]   12800000  (csr_compact = first 6.4MB; dead before pullx writes)
    //   26020096  agg1      [50000*128]  25600000  (pairs_static 196*10240*4=8028160 overlays; dead before gemm1b)
    //   51620096  h2h (bf16)[50000*64]   6400000   -> end 58020096
    char* ws = (char*)d_ws;
    float*          dinv     = (float*)ws;
    float*          stats    = (float*)(ws + 200704);
    int*            bcursor  = (int*)(ws + 202752);
    int*            cbase    = (int*)(ws + 215296);
    int*            rowstart = (int*)(ws + 219392);
    unsigned int*   wsrc     = (unsigned int*)(ws + 420096);
    unsigned short* xh       = (unsigned short*)(ws + 6820096);
    float*          aggx     = (float*)(ws + 13220096);
    int*            csr      = (int*)(ws + 13220096);     // overlays aggx (dead before pullx)
    float*          agg1     = (float*)(ws + 26020096);
    int*            pairs    = (int*)(ws + 26020096);     // overlays agg1 (dead before gemm1b)
    unsigned short* h2h      = (unsigned short*)(ws + 51620096);

    const int nblk_cast  = (N_NODES * C1 / 4 + 255) / 256;   // 3125
    const int nblk_rows  = (N_NODES + 31) / 32;
    const int nblk_scat  = (E + STILE - 1) / STILE;          // 391
    const int nblk_edge  = (E + 255) / 256;
    const int nblk_pull  = (N_NODES + 3) / 4;

    k_zero_cast<<<nblk_cast, 256, 0, stream>>>(x, xh, bcursor, stats);
    k_scatterc<<<nblk_scat, 256, 0, stream>>>(src, dst, E, bcursor, pairs);
    k_scanb<<<1, 256, 0, stream>>>(bcursor, cbase);
    k_refine<<<NBUCK, 256, 0, stream>>>(bcursor, cbase, rowstart, dinv, pairs, csr);
    k_pack<<<nblk_edge, 256, 0, stream>>>(csr, dinv, wsrc, E);

    k_pullx<<<nblk_pull, 256, 0, stream>>>(rowstart, wsrc, x, xh, dinv, aggx);
    k_gemm1b<<<nblk_rows, 256, 0, stream>>>(aggx, W1, b1, agg1);

    k_stats<<<256, 256, 0, stream>>>(agg1, stats);
    k_bnparam<<<1, 128, 0, stream>>>(gamma, beta, stats);

    k_gemm2<<<nblk_rows, 256, 0, stream>>>(agg1, W2, stats, h2h);
    k_pull2<<<nblk_pull, 256, 0, stream>>>(rowstart, wsrc, h2h, dinv, b2, out);
}